// Round 7
// baseline (69.930 us; speedup 1.0000x reference)
//
#include <hip/hip_runtime.h>
#include <math.h>

#define NC 32
#define NSTEPS 32

constexpr int BLOCK = 256;
constexpr int PTS = 4;                 // 4 chains/thread; 32 waves/CU TLP
constexpr int CHUNK = BLOCK * PTS;     // 1024 points per block

// Fused kernel, DS-optimized: SoA coefficient tables so each gather phase
// touches all 32 banks with exactly ONE distinct address per bank (same-cell
// lanes broadcast-merge -> free). tab[0..31] = A_c, tab[32..63] = 32*B_c.
// The two reads tab[c] / tab[c+32] share a vaddr 128B apart -> ds_read2_b32.
//
// State z = 32*x (2^5 scale commutes exactly with fp32 RN rounding):
//   cell c = (int)med3(z, 0, 31.5)   == clip(floor(32x), 0, 31) bitwise
//   z' = fmaf(A, z, 32*B)            == 32 * fmaf(A, x, B) bitwise
__global__ void __launch_bounds__(BLOCK)
cpab_kernel(const float* __restrict__ points,
            const float* __restrict__ theta,
            const float* __restrict__ basis,
            float* __restrict__ out,
            int n_points, int d) {
    __shared__ float tab[2 * NC];      // [0..31] = A, [32..63] = 32*B

    const int blocks_per_theta = n_points / CHUNK;   // 256
    const int j = blockIdx.x / blocks_per_theta;
    const int tid = threadIdx.x;

    if (tid < NC) {
        const int c = tid;
        const float* __restrict__ th = theta + j * d;
        const float* __restrict__ ba = basis + (2 * c) * d;
        const float* __restrict__ bb = basis + (2 * c + 1) * d;
        float a = 0.0f, b = 0.0f;
#pragma unroll 6
        for (int k = 0; k < d; ++k) {
            float t = th[k];
            a = fmaf(ba[k], t, a);
            b = fmaf(bb[k], t, b);
        }
        const float dT = 1.0f / (float)NSTEPS;
        a *= dT;
        b *= dT;
        float A = expf(a);
        // phi(a) = (e^a - 1)/a, stable small-a branch (matches reference)
        float phi = (fabsf(a) < 1e-6f) ? (1.0f + 0.5f * a) : (expm1f(a) / a);
        tab[c]      = A;
        tab[c + NC] = 32.0f * (b * phi);   // exact 2^5 scale of B
    }
    __syncthreads();

    const int base = (blockIdx.x % blocks_per_theta) * CHUNK + tid * PTS;

    float z[PTS];
    {
        float4 v = *(const float4*)(points + base);
        z[0] = v.x * 32.0f; z[1] = v.y * 32.0f;      // exact 2^5 scale
        z[2] = v.z * 32.0f; z[3] = v.w * 32.0f;
    }

#pragma unroll
    for (int s = 0; s < NSTEPS; ++s) {
#pragma unroll
        for (int i = 0; i < PTS; ++i) {
            float zc = fminf(fmaxf(z[i], 0.0f), 31.5f); // v_med3_f32
            int c = (int)zc;                            // v_cvt_i32_f32
            float A  = tab[c];                          // ds_read2_b32
            float Bz = tab[c + NC];                     //   (merged pair)
            z[i] = fmaf(A, z[i], Bz);                   // v_fma_f32
        }
    }

    const float inv = 1.0f / 32.0f;                  // exact scale back
    float4 o = make_float4(z[0] * inv, z[1] * inv, z[2] * inv, z[3] * inv);
    *(float4*)(out + j * n_points + base) = o;
}

extern "C" void kernel_launch(void* const* d_in, const int* in_sizes, int n_in,
                              void* d_out, int out_size, void* d_ws, size_t ws_size,
                              hipStream_t stream) {
    const float* points = (const float*)d_in[0];  // [1, n_points]
    const float* theta  = (const float*)d_in[1];  // [n_theta, d]
    const float* basis  = (const float*)d_in[2];  // [2*NC, d]

    int n_points = in_sizes[0];
    int d        = in_sizes[2] / (2 * NC);        // 30
    int n_theta  = in_sizes[1] / d;               // 8

    int grid = n_theta * (n_points / CHUNK);      // 8 * 256 = 2048 blocks
    cpab_kernel<<<grid, BLOCK, 0, stream>>>(points, theta, basis,
                                            (float*)d_out, n_points, d);
}